// Round 2
// baseline (133.568 us; speedup 1.0000x reference)
//
#include <hip/hip_runtime.h>

#define NN 256
#define DD 128
#define OC 128
// pre layout per row: [ preA+bm1 (128) | preB (128) | h@Wu_top (128) ] = 384 f32 = 192 float2

// ---------------------------------------------------------------------------
// K1: pre = h @ [Wm1_top | Wm1_bot | Wu_top]  (+bm1 folded into region 0)
//     plus ai = h@Wa_top + ba,  aj = h@Wa_bot
// 512 blocks x 256 thr; block = 4 rows x 384 cols; K=128 chunked by 16 in LDS.
// thread: r = tid>>6 (row), g = tid&63 (col-pair); 3 float2 accumulators.
// ---------------------------------------------------------------------------
__global__ __launch_bounds__(256) void k1_pre(
    const float* __restrict__ h, const float* __restrict__ Wm1,
    const float* __restrict__ Wa, const float* __restrict__ bm1,
    const float* __restrict__ Wu, const float* __restrict__ ba,
    float* __restrict__ pre, float* __restrict__ aiv, float* __restrict__ ajv)
{
    const int tid  = threadIdx.x;
    const int row0 = blockIdx.x * 4;
    const int r    = tid >> 6;
    const int g    = tid & 63;

    __shared__ float h_sh[4][128];
    __shared__ float w_sh[16][384];

    const float2* h2    = (const float2*)h;
    const float2* Wm1_2 = (const float2*)Wm1;
    const float2* Wu_2  = (const float2*)Wu;
    const float2* Wa2   = (const float2*)Wa;

    ((float2*)h_sh)[tid] = h2[row0 * 64 + tid];
    __syncthreads();

    // ai/aj: wave r handles row r; lane g covers d-pair g
    {
        float2 hv = ((const float2*)h_sh[r])[g];
        float2 wt = Wa2[g], wb = Wa2[64 + g];
        float vi = hv.x * wt.x + hv.y * wt.y;
        float vj = hv.x * wb.x + hv.y * wb.y;
        #pragma unroll
        for (int o = 1; o < 64; o <<= 1) {
            vi += __shfl_xor(vi, o, 64);
            vj += __shfl_xor(vj, o, 64);
        }
        if (g == 0) { aiv[row0 + r] = vi + ba[0]; ajv[row0 + r] = vj; }
    }

    float2 a0{0.f,0.f}, a1{0.f,0.f}, a2{0.f,0.f};
    for (int c = 0; c < 8; ++c) {
        const int d0 = c * 16;
        __syncthreads();
        // stage 16x384 weight chunk: 3072 float2 / 256 thr = 12 each
        #pragma unroll
        for (int v = 0; v < 12; ++v) {
            int idx = tid + 256 * v;
            int dd = idx / 192, cc = idx % 192;
            int srow = d0 + dd;
            float2 val;
            if (cc < 64)       val = Wm1_2[srow * 64 + cc];
            else if (cc < 128) val = Wm1_2[(128 + srow) * 64 + (cc - 64)];
            else               val = Wu_2[srow * 64 + (cc - 128)];
            ((float2*)w_sh[dd])[cc] = val;
        }
        __syncthreads();
        #pragma unroll
        for (int dd = 0; dd < 16; ++dd) {
            const float hb = h_sh[r][d0 + dd];
            const float2* wr2 = (const float2*)w_sh[dd];
            float2 w0 = wr2[g], w1 = wr2[64 + g], w2v = wr2[128 + g];
            a0.x = fmaf(hb, w0.x,  a0.x); a0.y = fmaf(hb, w0.y,  a0.y);
            a1.x = fmaf(hb, w1.x,  a1.x); a1.y = fmaf(hb, w1.y,  a1.y);
            a2.x = fmaf(hb, w2v.x, a2.x); a2.y = fmaf(hb, w2v.y, a2.y);
        }
    }
    const float2 bb = ((const float2*)bm1)[g];
    a0.x += bb.x; a0.y += bb.y;
    float2* pre2 = (float2*)pre;
    const int rbase = (row0 + r) * 192;
    pre2[rbase + g]       = a0;
    pre2[rbase + 64 + g]  = a1;
    pre2[rbase + 128 + g] = a2;
}

// ---------------------------------------------------------------------------
// K2: per (b,i): masked softmax over j (shuffle reduce), then
//     t[k] = sum_j w_j * relu(preA'[i,k] + preB[j,k] + d_ij*Wm1[256,k])
// Wave wid owns j in [wid*64, wid*64+64); unmasked j are ballot-compacted so
// the inner loop is branch-free with uniform trip count.
// wsum == 1 (or 0 if row fully masked) -> stored as sflag.
// ---------------------------------------------------------------------------
__global__ __launch_bounds__(256) void k2_main(
    const int* __restrict__ adj, const float* __restrict__ dist,
    const float* __restrict__ Wm1, const float* __restrict__ Wa,
    const float* __restrict__ pre,
    const float* __restrict__ aiv, const float* __restrict__ ajv,
    float* __restrict__ tmat, float* __restrict__ sflag)
{
    const int row  = blockIdx.x;
    const int b    = row >> 8;
    const int tid  = threadIdx.x;
    const int lane = tid & 63;
    const int wid  = tid >> 6;

    __shared__ float4 cwd[4][64];
    __shared__ float  mx_sh[4], sm_sh[4];
    __shared__ float2 tred[4][64];

    const int   j  = tid;
    const float dv = dist[row * NN + j];
    const int   mk = adj[row * NN + j];

    float logit = aiv[row] + ajv[b * NN + j] + dv * Wa[2 * DD];
    logit = (logit >= 0.f) ? logit : 0.2f * logit;          // leaky_relu(0.2)
    const float lmask = mk ? logit : -1e9f;

    float m = lmask;
    #pragma unroll
    for (int o = 1; o < 64; o <<= 1) m = fmaxf(m, __shfl_xor(m, o, 64));
    if (lane == 0) mx_sh[wid] = m;
    __syncthreads();
    const float mx = fmaxf(fmaxf(mx_sh[0], mx_sh[1]), fmaxf(mx_sh[2], mx_sh[3]));

    float em = mk ? __expf(logit - mx) : 0.f;
    float s = em;
    #pragma unroll
    for (int o = 1; o < 64; o <<= 1) s += __shfl_xor(s, o, 64);
    if (lane == 0) sm_sh[wid] = s;
    __syncthreads();
    const float esum = sm_sh[0] + sm_sh[1] + sm_sh[2] + sm_sh[3];
    const float inv  = (esum > 0.f) ? (1.0f / esum) : 0.f;
    const float w    = em * inv;

    // ballot-compact this wave's unmasked j into cwd[wid][]
    const unsigned long long act = __ballot(w != 0.f);
    const int pos = __popcll(act & ((1ull << lane) - 1ull));
    const int cnt = __popcll(act);
    if (w != 0.f)
        cwd[wid][pos] = make_float4(w, dv, __int_as_float(j * 192), 0.f);
    __syncthreads();

    const float2* pre2 = (const float2*)pre;
    const float2  pa   = pre2[row * 192 + lane];                 // preA'+bm1
    const float2  wd1  = ((const float2*)Wm1)[(2 * DD * OC) / 2 + lane]; // d-coef
    const float2* pB   = pre2 + (size_t)b * NN * 192 + 64;       // preB region

    float2 acc{0.f, 0.f};
    for (int i = 0; i < cnt; ++i) {
        float4 c = cwd[wid][i];
        int off = __float_as_int(c.z);                            // j*192
        float2 pb = pB[off + lane];
        float vx = fmaf(c.y, wd1.x, pa.x + pb.x);
        float vy = fmaf(c.y, wd1.y, pa.y + pb.y);
        acc.x = fmaf(c.x, fmaxf(vx, 0.f), acc.x);
        acc.y = fmaf(c.x, fmaxf(vy, 0.f), acc.y);
    }
    tred[wid][lane] = acc;
    __syncthreads();
    if (tid < 64) {
        float2 t0 = tred[0][tid], t1 = tred[1][tid];
        float2 t2v = tred[2][tid], t3 = tred[3][tid];
        float2 tt{t0.x + t1.x + t2v.x + t3.x, t0.y + t1.y + t2v.y + t3.y};
        ((float2*)tmat)[row * 64 + tid] = tt;
    }
    if (tid == 0) sflag[row] = (esum > 0.f) ? 1.f : 0.f;
}

// ---------------------------------------------------------------------------
// K3: agg = t @ Wm2 + bm2*sflag ;  out = relu(hu + agg @ Wu_bot + bu)
// 256 blocks x 256 thr; block = 8 rows; both K=128 matmuls LDS-chunked by 16.
// thread: r = tid>>5 (row), g = tid&31 (col-pair; covers cols {2g, 64+2g}).
// ---------------------------------------------------------------------------
__global__ __launch_bounds__(256) void k3_out(
    const float* __restrict__ tmat, const float* __restrict__ sflag,
    const float* __restrict__ pre,
    const float* __restrict__ Wm2, const float* __restrict__ bm2,
    const float* __restrict__ Wu,  const float* __restrict__ bu,
    float* __restrict__ out)
{
    const int tid  = threadIdx.x;
    const int row0 = blockIdx.x * 8;
    const int r    = tid >> 5;
    const int g    = tid & 31;

    __shared__ float t_sh[8][128];
    __shared__ float agg_sh[8][128];
    __shared__ float w_sh[16][128];
    __shared__ float sf_sh[8];

    const float2* t2 = (const float2*)tmat;
    ((float2*)t_sh)[tid]       = t2[row0 * 64 + tid];
    ((float2*)t_sh)[tid + 256] = t2[row0 * 64 + tid + 256];
    if (tid < 8) sf_sh[tid] = sflag[row0 + tid];

    const float2* Wm2_2 = (const float2*)Wm2;
    const float2* Wu_2  = (const float2*)Wu;

    float2 a0{0.f,0.f}, a1{0.f,0.f};
    for (int c = 0; c < 8; ++c) {
        const int d0 = c * 16;
        __syncthreads();
        #pragma unroll
        for (int v = 0; v < 4; ++v) {
            int idx = tid + 256 * v;
            int dd = idx >> 6, cc = idx & 63;
            ((float2*)w_sh)[idx] = Wm2_2[(d0 + dd) * 64 + cc];
        }
        __syncthreads();
        #pragma unroll
        for (int dd = 0; dd < 16; ++dd) {
            const float tb = t_sh[r][d0 + dd];
            const float2* wr2 = (const float2*)w_sh[dd];
            float2 w0 = wr2[g], w1 = wr2[32 + g];
            a0.x = fmaf(tb, w0.x, a0.x); a0.y = fmaf(tb, w0.y, a0.y);
            a1.x = fmaf(tb, w1.x, a1.x); a1.y = fmaf(tb, w1.y, a1.y);
        }
    }
    const float sf = sf_sh[r];
    const float2 b0 = ((const float2*)bm2)[g], b1 = ((const float2*)bm2)[32 + g];
    ((float2*)agg_sh[r])[g]      = make_float2(fmaf(b0.x, sf, a0.x), fmaf(b0.y, sf, a0.y));
    ((float2*)agg_sh[r])[32 + g] = make_float2(fmaf(b1.x, sf, a1.x), fmaf(b1.y, sf, a1.y));

    a0 = make_float2(0.f, 0.f); a1 = make_float2(0.f, 0.f);
    for (int c = 0; c < 8; ++c) {
        const int d0 = c * 16;
        __syncthreads();
        #pragma unroll
        for (int v = 0; v < 4; ++v) {
            int idx = tid + 256 * v;
            int dd = idx >> 6, cc = idx & 63;
            ((float2*)w_sh)[idx] = Wu_2[(128 + d0 + dd) * 64 + cc];
        }
        __syncthreads();
        #pragma unroll
        for (int dd = 0; dd < 16; ++dd) {
            const float ab = agg_sh[r][d0 + dd];
            const float2* wr2 = (const float2*)w_sh[dd];
            float2 w0 = wr2[g], w1 = wr2[32 + g];
            a0.x = fmaf(ab, w0.x, a0.x); a0.y = fmaf(ab, w0.y, a0.y);
            a1.x = fmaf(ab, w1.x, a1.x); a1.y = fmaf(ab, w1.y, a1.y);
        }
    }

    const float2* pre2 = (const float2*)pre;
    const int prow = (row0 + r) * 192 + 128;                 // hu region
    float2 hu0 = pre2[prow + g], hu1 = pre2[prow + 32 + g];
    float2 c0 = ((const float2*)bu)[g], c1 = ((const float2*)bu)[32 + g];
    float2 o0{fmaxf(a0.x + hu0.x + c0.x, 0.f), fmaxf(a0.y + hu0.y + c0.y, 0.f)};
    float2 o1{fmaxf(a1.x + hu1.x + c1.x, 0.f), fmaxf(a1.y + hu1.y + c1.y, 0.f)};
    float2* out2 = (float2*)out;
    out2[(row0 + r) * 64 + g]      = o0;
    out2[(row0 + r) * 64 + 32 + g] = o1;
}

extern "C" void kernel_launch(void* const* d_in, const int* in_sizes, int n_in,
                              void* d_out, int out_size, void* d_ws, size_t ws_size,
                              hipStream_t stream) {
    const float* h    = (const float*)d_in[0];
    const int*   adj  = (const int*)  d_in[1];
    const float* dist = (const float*)d_in[2];
    const float* Wm1  = (const float*)d_in[3];
    const float* bm1  = (const float*)d_in[4];
    const float* Wm2  = (const float*)d_in[5];
    const float* bm2  = (const float*)d_in[6];
    const float* Wa   = (const float*)d_in[7];
    const float* ba   = (const float*)d_in[8];
    const float* Wu   = (const float*)d_in[9];
    const float* bu   = (const float*)d_in[10];
    float* out = (float*)d_out;

    float* pre   = (float*)d_ws;                  // 2048*384 f32 = 3 MB
    float* aiv   = pre + 2048 * 384;              // 2048
    float* ajv   = aiv + 2048;                    // 2048
    float* tmat  = ajv + 2048;                    // 2048*128 = 1 MB
    float* sfl   = tmat + 2048 * 128;             // 2048

    k1_pre <<<512, 256, 0, stream>>>(h, Wm1, Wa, bm1, Wu, ba, pre, aiv, ajv);
    k2_main<<<2048, 256, 0, stream>>>(adj, dist, Wm1, Wa, pre, aiv, ajv, tmat, sfl);
    k3_out <<<256, 256, 0, stream>>>(tmat, sfl, pre, Wm2, bm2, Wu, bu, out);
}